// Round 4
// baseline (335.922 us; speedup 1.0000x reference)
//
#include <hip/hip_runtime.h>
#include <hip/hip_cooperative_groups.h>
#include <math.h>

namespace cg = cooperative_groups;

// Capsule routing, u_hat never materialized (factors through W):
//   v[b,n,c] = sum_i c[b,n,i] u[b,i,c]
//   s[b,n,d] = sum_c v[b,n,c] W[c,n*64+d];  o = squash(s)
//   t[b,n,c] = sum_d o[b,n,d] W[c,n*64+d]
//   b[b,n,i] = sum_c t[b,n,c] u[b,i,c]
// Iter 0: b=0 -> c uniform 1/32 -> v0 = colsum(u)/32.
//
// R4: R3's coop persistent kernel failed silently (absmax == max|ref| -> out
// never written -> unchecked hipLaunchCooperativeKernel rejection; LDS was
// 74.5 KB/block). Fixes: (a) u tile stored bf16 -> LDS 50.7 KB; (b) occupancy
// pre-check + checked coop launch + segmented-phase fallback (same kernel,
// normal launches, no grid.sync) so the kernel ALWAYS runs; (c) route inner
// loops use aligned b128 LDS reads + float4 broadcasts.

constexpr int Bn = 32, In = 1024, Cn = 256, Nn = 32, Dn = 64, ND = 2048;

#define UNPK(p, lo, hi)                      \
  lo = __uint_as_float((p) << 16);           \
  hi = __uint_as_float((p) & 0xffff0000u)

__device__ __forceinline__ unsigned int packbf2(float a, float b) {
  unsigned int xa = __float_as_uint(a), xb = __float_as_uint(b);
  xa = (xa + 0x7fffu + ((xa >> 16) & 1u)) >> 16;  // RNE
  xb = (xb + 0x7fffu + ((xb >> 16) & 1u)) >> 16;
  return xa | (xb << 16);
}

// ---------------- W [Cn][ND] -> Wt [ND][Cn] ---------------------------------
__global__ void k_transpose(const float* __restrict__ W, float* __restrict__ Wt) {
  __shared__ float tile[64][65];
  int x0 = blockIdx.x * 64, y0 = blockIdx.y * 64;
  int lx = threadIdx.x & 63, ly = threadIdx.x >> 6;
#pragma unroll
  for (int k = 0; k < 16; ++k) {
    int y = ly + k * 4;
    tile[y][lx] = W[(size_t)(y0 + y) * ND + x0 + lx];
  }
  __syncthreads();
#pragma unroll
  for (int k = 0; k < 16; ++k) {
    int y = ly + k * 4;
    Wt[(size_t)(x0 + y) * Cn + y0 + lx] = tile[lx][y];
  }
}

// ---------------- persistent / segmented capsule kernel ---------------------
// grid = 512 blocks (z = b*16 + it), block = 512 threads (8 waves).
// LDS: u_l bf16 64x(132 uints) = 33792 B + sm f32[4224] = 16896 B -> 50688 B.
// phase: -1 = full coop (grid.sync); 0..5 = segmented single stage.
__global__ __launch_bounds__(512, 4) void k_caps(
    const float* __restrict__ u, const float* __restrict__ W,
    const float* __restrict__ Wt, float* psu, float* pv,
    float* __restrict__ tb, float* __restrict__ out, int phase) {
  const int z = blockIdx.x;            // 0..511
  const int b = z >> 4, it0 = (z & 15) * 64;
  const int tid = threadIdx.x;
  const int lane = tid & 63, w = tid >> 6;

  __shared__ unsigned int u_l[64][132];        // bf16 pairs; row stride 132 dw (4 mod 32 -> b128 min conflicts)
  __shared__ __align__(16) float sm[4224];     // t-half [32][132] / bb [32][68] / sst / colsum scratch

  // sst mapping: half h handles (b,n) pair bn2 = 2z + h
  const int h = tid >> 8, sc = tid & 255;
  const int bn2 = z * 2 + h, b2 = bn2 >> 5, n2 = bn2 & 31;

  // ---- stage u tile (fp32 global -> bf16 LDS); optional exact fp32 colsum --
  auto stage_u = [&](bool doColsum) {
    const float* up = u + ((size_t)(b * In + it0)) * Cn;
    float col0 = 0.f, col1 = 0.f, col2 = 0.f, col3 = 0.f;
#pragma unroll
    for (int k = 0; k < 8; ++k) {
      int idx = tid + k * 512;
      int row = idx >> 6, c4 = idx & 63;
      const float4 v = *(const float4*)&up[(size_t)row * Cn + c4 * 4];
      *(uint2*)&u_l[row][c4 * 2] = make_uint2(packbf2(v.x, v.y), packbf2(v.z, v.w));
      col0 += v.x; col1 += v.y; col2 += v.z; col3 += v.w;
    }
    if (doColsum) {
      int g = tid >> 6, c4 = tid & 63;
      sm[g * 256 + c4 * 4 + 0] = col0;
      sm[g * 256 + c4 * 4 + 1] = col1;
      sm[g * 256 + c4 * 4 + 2] = col2;
      sm[g * 256 + c4 * 4 + 3] = col3;
      __syncthreads();
      if (tid < 256) {
        float s = 0.f;
#pragma unroll
        for (int g2 = 0; g2 < 8; ++g2) s += sm[g2 * 256 + tid];
        psu[(size_t)z * 256 + tid] = s;
      }
    }
    __syncthreads();
  };

  // ---- fused v-reduce -> s -> squash -> t (two (b,n) pairs per block) ------
  float* vs  = sm;          // [512]
  float* red = sm + 512;    // [512]
  float* ol  = sm + 1024;   // [128]
  auto sstf = [&](const float* p, int count, int cstride, float scale,
                  bool writeT, bool writeOut) {
    float s = 0.f;
    for (int ch = 0; ch < count; ++ch) s += p[(size_t)ch * cstride];
    vs[h * 256 + sc] = s * scale;
    __syncthreads();
    {  // s partials: thread (q = sc>>6, d = sc&63) covers 64 c's
      int q = sc >> 6, d = sc & 63;
      const float* wp = W + (size_t)n2 * Dn + d;
      const float* vv = vs + h * 256 + q * 64;
      float a = 0.f;
#pragma unroll 8
      for (int c2 = 0; c2 < 64; ++c2) a += vv[c2] * wp[(size_t)(q * 64 + c2) * ND];
      red[h * 256 + q * 64 + d] = a;
    }
    __syncthreads();
    if (sc < 64) {  // squash: waves 0 and 4 (full waves)
      int d = sc;
      float a = red[h * 256 + d] + red[h * 256 + 64 + d] +
                red[h * 256 + 128 + d] + red[h * 256 + 192 + d];
      float sq = a * a;
#pragma unroll
      for (int off = 32; off > 0; off >>= 1) sq += __shfl_xor(sq, off, 64);
      float o = a / sqrtf(sq + 1e-7f);
      ol[h * 64 + d] = o;
      if (writeOut) out[(size_t)bn2 * Dn + d] = o;
    }
    __syncthreads();
    if (writeT) {  // t[c] = sum_d o[d] Wt[n*64+d][c], coalesced
      const float* wtp = Wt + (size_t)(n2 * Dn) * Cn + sc;
      float a = 0.f;
#pragma unroll 8
      for (int d = 0; d < Dn; ++d) a += ol[h * 64 + d] * wtp[(size_t)d * Cn];
      tb[(size_t)bn2 * Cn + sc] = a;
    }
    __syncthreads();
  };

  // ---- route: bb = t.u^T (from resident u_l) -> softmax -> pv partials -----
  auto route = [&]() {
    float acc[4] = {0.f, 0.f, 0.f, 0.f};
    for (int hk = 0; hk < 2; ++hk) {         // two 128-c halves of t in sm
      int C0 = hk * 128;
#pragma unroll
      for (int k = 0; k < 2; ++k) {          // stage t half 32x128 fp32
        int idx = tid + k * 512;
        int n = idx >> 5, c4 = idx & 31;
        *(float4*)&sm[n * 132 + c4 * 4] =
            *(const float4*)&tb[(size_t)(b * Nn + n) * Cn + C0 + c4 * 4];
      }
      __syncthreads();
      for (int s8 = 0; s8 < 16; ++s8) {      // 8 c per step
        const uint4 uu = *(const uint4*)&u_l[lane][(C0 >> 1) + s8 * 4];
        float u0, u1, u2, u3, u4, u5, u6, u7;
        UNPK(uu.x, u0, u1); UNPK(uu.y, u2, u3);
        UNPK(uu.z, u4, u5); UNPK(uu.w, u6, u7);
#pragma unroll
        for (int k = 0; k < 4; ++k) {
          const float4 t0 = *(const float4*)&sm[(4 * w + k) * 132 + s8 * 8];
          const float4 t1 = *(const float4*)&sm[(4 * w + k) * 132 + s8 * 8 + 4];
          acc[k] += t0.x * u0 + t0.y * u1 + t0.z * u2 + t0.w * u3 +
                    t1.x * u4 + t1.y * u5 + t1.z * u6 + t1.w * u7;
        }
      }
      __syncthreads();
    }
    // bb into sm as [32][68]
#pragma unroll
    for (int k = 0; k < 4; ++k) sm[(4 * w + k) * 68 + lane] = acc[k];
    __syncthreads();
    if (tid < 64) {  // softmax over n, in place
      float m = -1e30f;
#pragma unroll
      for (int n = 0; n < Nn; ++n) m = fmaxf(m, sm[n * 68 + tid]);
      float e[Nn];
      float ssum = 0.f;
#pragma unroll
      for (int n = 0; n < Nn; ++n) { e[n] = __expf(sm[n * 68 + tid] - m); ssum += e[n]; }
      float inv = 1.f / ssum;
#pragma unroll
      for (int n = 0; n < Nn; ++n) sm[n * 68 + tid] = e[n] * inv;
    }
    __syncthreads();
    // pv partials: wave w -> n in {4w..4w+3}, lane -> c = 4*lane..4*lane+3
    float a2[4][4];
#pragma unroll
    for (int k = 0; k < 4; ++k)
#pragma unroll
      for (int j = 0; j < 4; ++j) a2[k][j] = 0.f;
    for (int i4 = 0; i4 < 64; i4 += 4) {
      float4 cv[4];
#pragma unroll
      for (int k = 0; k < 4; ++k) cv[k] = *(const float4*)&sm[(4 * w + k) * 68 + i4];
#pragma unroll
      for (int j = 0; j < 4; ++j) {
        const uint2 up2 = *(const uint2*)&u_l[i4 + j][2 * lane];
        float f0, f1, f2, f3;
        UNPK(up2.x, f0, f1); UNPK(up2.y, f2, f3);
#pragma unroll
        for (int k = 0; k < 4; ++k) {
          float c1 = (j == 0) ? cv[k].x : (j == 1) ? cv[k].y : (j == 2) ? cv[k].z : cv[k].w;
          a2[k][0] += c1 * f0; a2[k][1] += c1 * f1;
          a2[k][2] += c1 * f2; a2[k][3] += c1 * f3;
        }
      }
    }
#pragma unroll
    for (int k = 0; k < 4; ++k)
      *(float4*)&pv[((size_t)(z * Nn + 4 * w + k)) * Cn + 4 * lane] =
          make_float4(a2[k][0], a2[k][1], a2[k][2], a2[k][3]);
    __syncthreads();
  };

  const float* p0 = psu + (size_t)b2 * 4096 + sc;                       // iter-0 src
  const float* p1 = pv + (size_t)b2 * 131072 + (size_t)n2 * 256 + sc;   // iter-1/2 src

  if (phase < 0) {
    auto gsync = [&]() { __threadfence(); cg::this_grid().sync(); };
    stage_u(true);
    gsync();
    sstf(p0, 16, 256, 1.0f / 32.0f, true, false);
    gsync();
    route();
    gsync();
    sstf(p1, 16, 8192, 1.0f, true, false);
    gsync();
    route();
    gsync();
    sstf(p1, 16, 8192, 1.0f, false, true);
  } else if (phase == 0) {
    stage_u(true);
  } else if (phase == 1) {
    sstf(p0, 16, 256, 1.0f / 32.0f, true, false);
  } else if (phase == 2 || phase == 4) {
    stage_u(false);
    route();
  } else if (phase == 3) {
    sstf(p1, 16, 8192, 1.0f, true, false);
  } else {
    sstf(p1, 16, 8192, 1.0f, false, true);
  }
}

extern "C" void kernel_launch(void* const* d_in, const int* in_sizes, int n_in,
                              void* d_out, int out_size, void* d_ws, size_t ws_size,
                              hipStream_t stream) {
  (void)in_sizes; (void)n_in; (void)out_size; (void)ws_size;
  const float* u = (const float*)d_in[0];   // (32,1024,256)
  const float* W = (const float*)d_in[1];   // (256,2048)
  float* out = (float*)d_out;               // (32,32,64)
  float* ws = (float*)d_ws;
  // workspace (floats): pv 4194304 (psu 131072 overlaid; psu dead before pv
  // written) + Wt 524288 + tb 262144 = 19.0 MB
  float* pv  = ws;
  float* psu = ws;
  float* Wt  = ws + 4194304;
  float* tbb = ws + 4718592;

  k_transpose<<<dim3(32, 4), 256, 0, stream>>>(W, Wt);

  // Coop pre-check (pure query, capture-safe): need 2 blocks/CU co-resident.
  int nb = 0;
  hipError_t qe = hipOccupancyMaxActiveBlocksPerMultiprocessor(
      &nb, (const void*)k_caps, 512, 0);
  hipError_t le = hipErrorUnknown;
  if (qe == hipSuccess && nb >= 2) {
    int phm1 = -1;
    void* args[] = {(void*)&u, (void*)&W, (void*)&Wt, (void*)&psu,
                    (void*)&pv, (void*)&tbb, (void*)&out, (void*)&phm1};
    le = hipLaunchCooperativeKernel((const void*)k_caps, dim3(512), dim3(512),
                                    args, 0, stream);
  }
  if (le != hipSuccess) {
    (void)hipGetLastError();  // clear any sticky error; run segmented path
    k_caps<<<512, 512, 0, stream>>>(u, W, Wt, psu, pv, tbb, out, 0);
    k_caps<<<512, 512, 0, stream>>>(u, W, Wt, psu, pv, tbb, out, 1);
    k_caps<<<512, 512, 0, stream>>>(u, W, Wt, psu, pv, tbb, out, 2);
    k_caps<<<512, 512, 0, stream>>>(u, W, Wt, psu, pv, tbb, out, 3);
    k_caps<<<512, 512, 0, stream>>>(u, W, Wt, psu, pv, tbb, out, 4);
    k_caps<<<512, 512, 0, stream>>>(u, W, Wt, psu, pv, tbb, out, 5);
  }
}

// Round 5
// 188.322 us; speedup vs baseline: 1.7838x; 1.7838x over previous
//
#include <hip/hip_runtime.h>
#include <math.h>

// Capsule routing, u_hat never materialized (factors through W):
//   v[b,n,c] = sum_i c[b,n,i] u[b,i,c]
//   s[b,n,d] = sum_c v[b,n,c] W[c,n*64+d];  o = squash(s)
//   t[b,n,c] = sum_d o[b,n,d] W[c,n*64+d]
//   b[b,n,i] = sum_c t[b,n,c] u[b,i,c]
// Iter 0: b=0 -> c uniform 1/32 -> v0 = colsum(u)/32.
//
// R5: cooperative grid.sync measured ~1000 us/dispatch with 516 MB WRITE
// (spin traffic) -- abandoned. Segmented launches (6, no transpose), with
// k_route rebuilt for occupancy: 256-thr blocks, i-tile=32, 1024 blocks
// (4 blocks/CU, 16 waves/CU), u+t staged bf16 once (38 KB LDS, stride-130-dw
// rows: every access mode <=2-way bank conflict = free), ~4 barriers/kernel
// instead of R2's barrier-every-256-FMA.
// WS assumption: ws_size >= 35 MB (R2 proved >= 19 MB worked).

constexpr int Bn = 32, In = 1024, Cn = 256, Nn = 32, Dn = 64, ND = 2048;

#define UNPK(p, lo, hi)                      \
  lo = __uint_as_float((p) << 16);           \
  hi = __uint_as_float((p) & 0xffff0000u)

__device__ __forceinline__ unsigned int packbf2(float a, float b) {
  unsigned int xa = __float_as_uint(a), xb = __float_as_uint(b);
  xa = (xa + 0x7fffu + ((xa >> 16) & 1u)) >> 16;  // RNE
  xb = (xb + 0x7fffu + ((xb >> 16) & 1u)) >> 16;
  return xa | (xb << 16);
}

// ---------------- psu[(b*32+ch)*256+c] = sum over 32 i of u[b,i,c] ----------
__global__ __launch_bounds__(256) void k_colsum(const float* __restrict__ u,
                                                float* __restrict__ psu) {
  int b = blockIdx.x, ch = blockIdx.y, c = threadIdx.x;
  const float* up = u + ((size_t)(b * In + ch * 32)) * Cn + c;
  float s = 0.f;
#pragma unroll 8
  for (int j = 0; j < 32; ++j) s += up[(size_t)j * Cn];
  psu[(size_t)(b * 32 + ch) * Cn + c] = s;
}

// ---- fused: v-reduce -> s -> squash -> [out] -> [t] ------------------------
// Block bn = b*32+n, 256 threads. v source: src + b*bS + n*nS + ch*cS + c.
__global__ __launch_bounds__(256) void k_sst(
    const float* __restrict__ src, int count, int bS, int nS, int cS,
    float scale, const float* __restrict__ W, float* __restrict__ tb,
    float* __restrict__ outp, int writeT) {
  int bn = blockIdx.x, b = bn >> 5, n = bn & 31;
  int tid = threadIdx.x;
  __shared__ float vs[Cn];
  __shared__ float red[Cn];
  __shared__ float ol[Dn];
  {  // v-reduce (lanes = c, coalesced 1 KB per chunk)
    const float* p = src + (size_t)b * bS + (size_t)n * nS + tid;
    float s = 0.f;
    for (int ch = 0; ch < count; ++ch) s += p[(size_t)ch * cS];
    vs[tid] = s * scale;
  }
  __syncthreads();
  {  // s partials: thread (q = tid>>6 wave, d = tid&63) covers 64 c's
    int q = tid >> 6, d = tid & 63;
    const float* wp = W + (size_t)(q * 64) * ND + (size_t)n * Dn + d;
    const float* vv = vs + q * 64;
    float a = 0.f;
#pragma unroll 8
    for (int c2 = 0; c2 < 64; ++c2) a += vv[c2] * wp[(size_t)c2 * ND];
    red[q * 64 + d] = a;
  }
  __syncthreads();
  if (tid < 64) {  // squash (one full wave)
    float a = red[tid] + red[64 + tid] + red[128 + tid] + red[192 + tid];
    float sq = a * a;
#pragma unroll
    for (int off = 32; off > 0; off >>= 1) sq += __shfl_xor(sq, off, 64);
    float o = a / sqrtf(sq + 1e-7f);
    ol[tid] = o;
    if (outp) outp[(size_t)bn * Dn + tid] = o;
  }
  __syncthreads();
  if (writeT) {  // t[c] = sum_d ol[d] * W[c][n*64+d]; lane c reads 256 B dense
    const float* wp = W + (size_t)tid * ND + (size_t)n * Dn;
    float a = 0.f;
#pragma unroll
    for (int d4 = 0; d4 < 16; ++d4) {
      const float4 w4 = *(const float4*)&wp[d4 * 4];
      a += w4.x * ol[d4 * 4] + w4.y * ol[d4 * 4 + 1] +
           w4.z * ol[d4 * 4 + 2] + w4.w * ol[d4 * 4 + 3];
    }
    tb[(size_t)bn * Cn + tid] = a;
  }
}

// ---- fused routing step: bb = t.u^T -> softmax over n -> pv partials -------
// Block (b, it): i-tile of 32, 256 threads (4 waves). u,t bf16 in LDS.
__global__ __launch_bounds__(256, 4) void k_route(
    const float* __restrict__ tb, const float* __restrict__ u,
    float* __restrict__ pv) {
  const int b = blockIdx.x, it = blockIdx.y, i0 = it * 32;
  const int tid = threadIdx.x;
  const int lane = tid & 63, w = tid >> 6;

  __shared__ unsigned int u_l[32][130];  // bf16 pairs; 130-dw stride: <=2-way
  __shared__ unsigned int t_l[32][130];
  __shared__ float bb_l[32][36];

  // ---- stage u 32x256 and t 32x256 (fp32 -> bf16), coalesced float4 ----
  {
    const float* up = u + ((size_t)(b * In + i0)) * Cn;
    const float* tp = tb + (size_t)b * Nn * Cn;
#pragma unroll
    for (int k = 0; k < 8; ++k) {
      int idx = tid + k * 256;          // 2048 = 32 rows x 64 quads
      int row = idx >> 6, q = idx & 63;
      const float4 v = *(const float4*)&up[(size_t)row * Cn + q * 4];
      *(uint2*)&u_l[row][q * 2] = make_uint2(packbf2(v.x, v.y), packbf2(v.z, v.w));
      const float4 t4 = *(const float4*)&tp[(size_t)row * Cn + q * 4];
      *(uint2*)&t_l[row][q * 2] = make_uint2(packbf2(t4.x, t4.y), packbf2(t4.z, t4.w));
    }
  }
  __syncthreads();

  // ---- phase A: bb[n][i] = sum_c t[n,c] u[i,c] ----
  // lane: i = lane&31, hn = lane>>5; wave w -> n = w*8 + hn*4 + {0..3}
  {
    const int i = lane & 31;
    const int n0 = w * 8 + (lane >> 5) * 4;
    float a0 = 0.f, a1 = 0.f, a2 = 0.f, a3 = 0.f;
#pragma unroll 4
    for (int cq = 0; cq < 64; ++cq) {  // 4 c per step
      const uint2 uu = *(const uint2*)&u_l[i][cq * 2];
      float u0, u1, u2, u3;
      UNPK(uu.x, u0, u1); UNPK(uu.y, u2, u3);
      const uint2 t0 = *(const uint2*)&t_l[n0 + 0][cq * 2];
      const uint2 t1 = *(const uint2*)&t_l[n0 + 1][cq * 2];
      const uint2 t2 = *(const uint2*)&t_l[n0 + 2][cq * 2];
      const uint2 t3 = *(const uint2*)&t_l[n0 + 3][cq * 2];
      float f0, f1, f2, f3;
      UNPK(t0.x, f0, f1); UNPK(t0.y, f2, f3);
      a0 += f0 * u0 + f1 * u1 + f2 * u2 + f3 * u3;
      UNPK(t1.x, f0, f1); UNPK(t1.y, f2, f3);
      a1 += f0 * u0 + f1 * u1 + f2 * u2 + f3 * u3;
      UNPK(t2.x, f0, f1); UNPK(t2.y, f2, f3);
      a2 += f0 * u0 + f1 * u1 + f2 * u2 + f3 * u3;
      UNPK(t3.x, f0, f1); UNPK(t3.y, f2, f3);
      a3 += f0 * u0 + f1 * u1 + f2 * u2 + f3 * u3;
    }
    bb_l[n0 + 0][i] = a0;
    bb_l[n0 + 1][i] = a1;
    bb_l[n0 + 2][i] = a2;
    bb_l[n0 + 3][i] = a3;
  }
  __syncthreads();

  // ---- softmax over n per i (32 threads) ----
  if (tid < 32) {
    float m = -1e30f;
#pragma unroll
    for (int n = 0; n < Nn; ++n) m = fmaxf(m, bb_l[n][tid]);
    float e[Nn];
    float ssum = 0.f;
#pragma unroll
    for (int n = 0; n < Nn; ++n) { e[n] = __expf(bb_l[n][tid] - m); ssum += e[n]; }
    float inv = 1.f / ssum;
#pragma unroll
    for (int n = 0; n < Nn; ++n) bb_l[n][tid] = e[n] * inv;
  }
  __syncthreads();

  // ---- phase B: pv[n][c] = sum_i c[n,i] u[i,c] ----
  // wave w -> n = 8w..8w+7; lane -> c = 4*lane..4*lane+3
  {
    float a[8][4];
#pragma unroll
    for (int k = 0; k < 8; ++k)
#pragma unroll
      for (int j = 0; j < 4; ++j) a[k][j] = 0.f;
#pragma unroll 4
    for (int i = 0; i < 32; ++i) {
      const uint2 uu = *(const uint2*)&u_l[i][lane * 2];
      float f0, f1, f2, f3;
      UNPK(uu.x, f0, f1); UNPK(uu.y, f2, f3);
#pragma unroll
      for (int k = 0; k < 8; ++k) {
        const float cv = bb_l[w * 8 + k][i];  // wave-uniform broadcast
        a[k][0] += cv * f0; a[k][1] += cv * f1;
        a[k][2] += cv * f2; a[k][3] += cv * f3;
      }
    }
#pragma unroll
    for (int k = 0; k < 8; ++k)
      *(float4*)&pv[((size_t)((b * 32 + it) * Nn + w * 8 + k)) * Cn + lane * 4] =
          make_float4(a[k][0], a[k][1], a[k][2], a[k][3]);
  }
}

extern "C" void kernel_launch(void* const* d_in, const int* in_sizes, int n_in,
                              void* d_out, int out_size, void* d_ws, size_t ws_size,
                              hipStream_t stream) {
  (void)in_sizes; (void)n_in; (void)out_size; (void)ws_size;
  const float* u = (const float*)d_in[0];   // (32,1024,256)
  const float* W = (const float*)d_in[1];   // (256,2048)
  float* out = (float*)d_out;               // (32,32,64)
  float* ws = (float*)d_ws;
  // workspace (floats): pv 32*32*32*256 = 8388608 (33.6 MB; psu 262144
  // overlaid -- psu consumed by sst0 before route writes pv), tb 262144.
  float* pv  = ws;
  float* psu = ws;
  float* tbb = ws + 8388608;

  k_colsum<<<dim3(32, 32), 256, 0, stream>>>(u, psu);
  // iter 0: v0 = colsum/32  (psu: b*8192 + ch*256 + c)
  k_sst<<<1024, 256, 0, stream>>>(psu, 32, 8192, 0, 256, 1.0f / 32.0f,
                                  W, tbb, nullptr, 1);
  // iter 1
  k_route<<<dim3(32, 32), 256, 0, stream>>>(tbb, u, pv);
  // pv: b*262144 + it*8192 + n*256 + c
  k_sst<<<1024, 256, 0, stream>>>(pv, 32, 262144, 256, 8192, 1.0f,
                                  W, tbb, nullptr, 1);
  // iter 2 (final)
  k_route<<<dim3(32, 32), 256, 0, stream>>>(tbb, u, pv);
  k_sst<<<1024, 256, 0, stream>>>(pv, 32, 262144, 256, 8192, 1.0f,
                                  W, tbb, out, 0);
}

// Round 6
// 166.786 us; speedup vs baseline: 2.0141x; 1.1291x over previous
//
#include <hip/hip_runtime.h>
#include <math.h>

// Capsule routing, u_hat never materialized (factors through W):
//   v[b,n,c] = sum_i c[b,n,i] u[b,i,c]
//   s[b,n,d] = sum_c v[b,n,c] W[c,n*64+d];  o = squash(s)
//   t[b,n,c] = sum_d o[b,n,d] W[c,n*64+d]
//   b[b,n,i] = sum_c t[b,n,c] u[b,i,c]
// Iter 0: b=0 -> c uniform 1/32 -> v0 = colsum(u)/32.
//
// R6: k_route phases A/B converted to mfma_f32_16x16x32_bf16.
//   A: D[i,n] = sum_c u[i,c] t[n,c]  (A-frag from global u fp32->bf16 pack,
//      B-frag b128 from t_l; 8 MFMA/wave vs ~2300 VALU instr in R5)
//   B: D[n,c] = sum_i c[n,i] u[i,c]  (K=32 -> 1 MFMA/tile; u_t i-major in
//      LDS built by scatter during staging; c packed bf16)
// LDS 44 KB -> 3 blocks/CU. grid.sync remains banned (R4: ~1000us, 516MB
// spin WRITE). Fills (harness 0xAA ws poison, 43us) dominate top-5 — all
// our kernels are under 43us now.

constexpr int Bn = 32, In = 1024, Cn = 256, Nn = 32, Dn = 64, ND = 2048;

typedef __attribute__((ext_vector_type(8))) short bf16x8;
typedef __attribute__((ext_vector_type(4))) float f32x4;

__device__ __forceinline__ unsigned int packbf2(float a, float b) {
  unsigned int xa = __float_as_uint(a), xb = __float_as_uint(b);
  xa = (xa + 0x7fffu + ((xa >> 16) & 1u)) >> 16;  // RNE
  xb = (xb + 0x7fffu + ((xb >> 16) & 1u)) >> 16;
  return xa | (xb << 16);
}
__device__ __forceinline__ unsigned short packbf1(float a) {
  unsigned int x = __float_as_uint(a);
  return (unsigned short)((x + 0x7fffu + ((x >> 16) & 1u)) >> 16);
}

// ---------------- psu[(b*32+ch)*256+c] = sum over 32 i of u[b,i,c] ----------
__global__ __launch_bounds__(256) void k_colsum(const float* __restrict__ u,
                                                float* __restrict__ psu) {
  int b = blockIdx.x, ch = blockIdx.y, c = threadIdx.x;
  const float* up = u + ((size_t)(b * In + ch * 32)) * Cn + c;
  float s = 0.f;
#pragma unroll 8
  for (int j = 0; j < 32; ++j) s += up[(size_t)j * Cn];
  psu[(size_t)(b * 32 + ch) * Cn + c] = s;
}

// ---- fused: v-reduce -> s -> squash -> [out] -> [t] ------------------------
__global__ __launch_bounds__(256) void k_sst(
    const float* __restrict__ src, int count, int bS, int nS, int cS,
    float scale, const float* __restrict__ W, float* __restrict__ tb,
    float* __restrict__ outp, int writeT) {
  int bn = blockIdx.x, b = bn >> 5, n = bn & 31;
  int tid = threadIdx.x;
  __shared__ float vs[Cn];
  __shared__ float red[Cn];
  __shared__ float ol[Dn];
  {  // v-reduce (lanes = c, coalesced 1 KB per chunk)
    const float* p = src + (size_t)b * bS + (size_t)n * nS + tid;
    float s = 0.f;
    for (int ch = 0; ch < count; ++ch) s += p[(size_t)ch * cS];
    vs[tid] = s * scale;
  }
  __syncthreads();
  {  // s partials: thread (q = tid>>6 wave, d = tid&63) covers 64 c's
    int q = tid >> 6, d = tid & 63;
    const float* wp = W + (size_t)(q * 64) * ND + (size_t)n * Dn + d;
    const float* vv = vs + q * 64;
    float a = 0.f;
#pragma unroll 8
    for (int c2 = 0; c2 < 64; ++c2) a += vv[c2] * wp[(size_t)c2 * ND];
    red[q * 64 + d] = a;
  }
  __syncthreads();
  if (tid < 64) {  // squash (one full wave)
    float a = red[tid] + red[64 + tid] + red[128 + tid] + red[192 + tid];
    float sq = a * a;
#pragma unroll
    for (int off = 32; off > 0; off >>= 1) sq += __shfl_xor(sq, off, 64);
    float o = a / sqrtf(sq + 1e-7f);
    ol[tid] = o;
    if (outp) outp[(size_t)bn * Dn + tid] = o;
  }
  __syncthreads();
  if (writeT) {  // t[c] = sum_d ol[d] * W[c][n*64+d]; lane c reads 256 B dense
    const float* wp = W + (size_t)tid * ND + (size_t)n * Dn;
    float a = 0.f;
#pragma unroll
    for (int d4 = 0; d4 < 16; ++d4) {
      const float4 w4 = *(const float4*)&wp[d4 * 4];
      a += w4.x * ol[d4 * 4] + w4.y * ol[d4 * 4 + 1] +
           w4.z * ol[d4 * 4 + 2] + w4.w * ol[d4 * 4 + 3];
    }
    tb[(size_t)bn * Cn + tid] = a;
  }
}

// ---- fused routing step (MFMA): bb = u.t^T -> softmax -> pv = c.u ----------
// Block (b, it): i-tile of 32, 256 threads (4 waves).
__global__ __launch_bounds__(256, 3) void k_route(
    const float* __restrict__ tb, const float* __restrict__ u,
    float* __restrict__ pv) {
  const int b = blockIdx.x, itile = blockIdx.y, i0 = itile * 32;
  const int tid = threadIdx.x;
  const int lane = tid & 63, w = tid >> 6;
  const int mrow = lane & 15, quad = lane >> 4;

  __shared__ unsigned short t_l[32][272];   // bf16, row 544 B (16B-mult, 8-bank skew)
  __shared__ unsigned short u_t[256][40];   // bf16 i-major, row 80 B
  __shared__ unsigned short cm_l[32][40];   // bf16 softmax(c), row 80 B
  __shared__ float bb_l[32][36];

  // ---- stage: t (row-major bf16) + u_t (i-major bf16 scatter) ----
  {
    const float* tp = tb + (size_t)b * Nn * Cn;
    const float* up = u + ((size_t)(b * In + i0)) * Cn;
#pragma unroll
    for (int k = 0; k < 8; ++k) {
      int idx = tid + k * 256;           // 2048 = 32 rows x 64 quads
      int row = idx >> 6, q = idx & 63;
      const float4 tv = *(const float4*)&tp[(size_t)row * Cn + q * 4];
      *(uint2*)&t_l[row][q * 4] =
          make_uint2(packbf2(tv.x, tv.y), packbf2(tv.z, tv.w));
      const float4 uv = *(const float4*)&up[(size_t)row * Cn + q * 4];
      u_t[q * 4 + 0][row] = packbf1(uv.x);
      u_t[q * 4 + 1][row] = packbf1(uv.y);
      u_t[q * 4 + 2][row] = packbf1(uv.z);
      u_t[q * 4 + 3][row] = packbf1(uv.w);
    }
  }
  __syncthreads();

  // ---- phase A: D[i,n] = sum_c u[i,c] t[n,c]; wave tile (i0t, n0t) ----
  {
    const int i0t = (w & 1) * 16, n0t = (w >> 1) * 16;
    const float* ub = u + ((size_t)(b * In + i0 + i0t + mrow)) * Cn + quad * 8;
    f32x4 acc = {0.f, 0.f, 0.f, 0.f};
#pragma unroll
    for (int k0 = 0; k0 < 8; ++k0) {       // c = k0*32 + quad*8 + j
      const float4 a0 = *(const float4*)(ub + k0 * 32);
      const float4 a1 = *(const float4*)(ub + k0 * 32 + 4);
      union { unsigned int ui[4]; bf16x8 v; } af;
      af.ui[0] = packbf2(a0.x, a0.y); af.ui[1] = packbf2(a0.z, a0.w);
      af.ui[2] = packbf2(a1.x, a1.y); af.ui[3] = packbf2(a1.z, a1.w);
      const bf16x8 bf = *(const bf16x8*)&t_l[n0t + mrow][k0 * 32 + quad * 8];
      acc = __builtin_amdgcn_mfma_f32_16x16x32_bf16(af.v, bf, acc, 0, 0, 0);
    }
    // D: col=lane&15 -> n within tile, row=quad*4+reg -> i within tile
#pragma unroll
    for (int r = 0; r < 4; ++r)
      bb_l[n0t + mrow][i0t + quad * 4 + r] = acc[r];
  }
  __syncthreads();

  // ---- softmax over n per i ----
  if (tid < 32) {
    float m = -1e30f;
#pragma unroll
    for (int n = 0; n < Nn; ++n) m = fmaxf(m, bb_l[n][tid]);
    float e[Nn];
    float ssum = 0.f;
#pragma unroll
    for (int n = 0; n < Nn; ++n) { e[n] = __expf(bb_l[n][tid] - m); ssum += e[n]; }
    float inv = 1.f / ssum;
#pragma unroll
    for (int n = 0; n < Nn; ++n) bb_l[n][tid] = e[n] * inv;
  }
  __syncthreads();

  // ---- pack c to bf16 (cm_l), 256 threads x 4 elems ----
  {
    int n = tid >> 3, q = tid & 7;
    const float4 cv = *(const float4*)&bb_l[n][q * 4];
    *(uint2*)&cm_l[n][q * 4] = make_uint2(packbf2(cv.x, cv.y), packbf2(cv.z, cv.w));
  }
  __syncthreads();

  // ---- phase B: D[n,c] = sum_i c[n,i] u[i,c]; K=32 -> 1 MFMA/tile ----
  {
    const int mt = w & 1;                  // ncap tile (0..1)
    const bf16x8 af = *(const bf16x8*)&cm_l[mt * 16 + mrow][quad * 8];
#pragma unroll
    for (int j = 0; j < 8; ++j) {
      const int ct = (w >> 1) * 8 + j;     // c tile (0..15)
      const bf16x8 bf = *(const bf16x8*)&u_t[ct * 16 + mrow][quad * 8];
      f32x4 d = {0.f, 0.f, 0.f, 0.f};
      d = __builtin_amdgcn_mfma_f32_16x16x32_bf16(af, bf, d, 0, 0, 0);
      // D: col=lane&15 -> c within tile, row=quad*4+reg -> ncap within tile
#pragma unroll
      for (int r = 0; r < 4; ++r)
        pv[((size_t)((b * 32 + itile) * Nn + mt * 16 + quad * 4 + r)) * Cn +
           ct * 16 + mrow] = d[r];
    }
  }
}

extern "C" void kernel_launch(void* const* d_in, const int* in_sizes, int n_in,
                              void* d_out, int out_size, void* d_ws, size_t ws_size,
                              hipStream_t stream) {
  (void)in_sizes; (void)n_in; (void)out_size; (void)ws_size;
  const float* u = (const float*)d_in[0];   // (32,1024,256)
  const float* W = (const float*)d_in[1];   // (256,2048)
  float* out = (float*)d_out;               // (32,32,64)
  float* ws = (float*)d_ws;
  // workspace (floats): pv 32*32*32*256 = 8388608 (33.6 MB; psu 262144
  // overlaid -- consumed by sst0 before route writes pv), tb 262144.
  float* pv  = ws;
  float* psu = ws;
  float* tbb = ws + 8388608;

  k_colsum<<<dim3(32, 32), 256, 0, stream>>>(u, psu);
  // iter 0: v0 = colsum/32  (psu: b*8192 + ch*256 + c)
  k_sst<<<1024, 256, 0, stream>>>(psu, 32, 8192, 0, 256, 1.0f / 32.0f,
                                  W, tbb, nullptr, 1);
  // iter 1
  k_route<<<dim3(32, 32), 256, 0, stream>>>(tbb, u, pv);
  // pv: b*262144 + it*8192 + n*256 + c
  k_sst<<<1024, 256, 0, stream>>>(pv, 32, 262144, 256, 8192, 1.0f,
                                  W, tbb, nullptr, 1);
  // iter 2 (final)
  k_route<<<dim3(32, 32), 256, 0, stream>>>(tbb, u, pv);
  k_sst<<<1024, 256, 0, stream>>>(pv, 32, 262144, 256, 8192, 1.0f,
                                  W, tbb, out, 0);
}

// Round 7
// 162.257 us; speedup vs baseline: 2.0703x; 1.0279x over previous
//
#include <hip/hip_runtime.h>
#include <math.h>

// Capsule routing, u_hat never materialized (factors through W):
//   v[b,n,c] = sum_i c[b,n,i] u[b,i,c]
//   s[b,n,d] = sum_c v[b,n,c] W[c,n*64+d];  o = squash(s)
//   t[b,n,c] = sum_d o[b,n,d] W[c,n*64+d]
//   b[b,n,i] = sum_c t[b,n,c] u[b,i,c]
// Iter 0: b=0 -> c uniform 1/32 -> v0 = colsum(u)/32.
//
// R7: k_sst's W loops were line-scattered (lane-stride 8 KB -> 64 cachelines
// per 64-lane load, ~27 us/dispatch by transaction arithmetic). Now each
// block stages its W[:, 64n:64n+64] slice coalesced into LDS as bf16
// Wl[256][68] (34.8 KB; stride 68 shorts -> s-step conflict-free, t-step
// <=4-way) and computes from LDS. fp32 accumulation throughout; W-bf16 only.
// grid.sync stays banned (R4: ~1000 us spin). Route unchanged from R6 (MFMA).

constexpr int Bn = 32, In = 1024, Cn = 256, Nn = 32, Dn = 64, ND = 2048;

typedef __attribute__((ext_vector_type(8))) short bf16x8;
typedef __attribute__((ext_vector_type(4))) float f32x4;

__device__ __forceinline__ unsigned int packbf2(float a, float b) {
  unsigned int xa = __float_as_uint(a), xb = __float_as_uint(b);
  xa = (xa + 0x7fffu + ((xa >> 16) & 1u)) >> 16;  // RNE
  xb = (xb + 0x7fffu + ((xb >> 16) & 1u)) >> 16;
  return xa | (xb << 16);
}
__device__ __forceinline__ unsigned short packbf1(float a) {
  unsigned int x = __float_as_uint(a);
  return (unsigned short)((x + 0x7fffu + ((x >> 16) & 1u)) >> 16);
}

// ---------------- psu[(b*32+ch)*256+c] = sum over 32 i of u[b,i,c] ----------
__global__ __launch_bounds__(256) void k_colsum(const float* __restrict__ u,
                                                float* __restrict__ psu) {
  int b = blockIdx.x, ch = blockIdx.y, c = threadIdx.x;
  const float* up = u + ((size_t)(b * In + ch * 32)) * Cn + c;
  float s = 0.f;
#pragma unroll 8
  for (int j = 0; j < 32; ++j) s += up[(size_t)j * Cn];
  psu[(size_t)(b * 32 + ch) * Cn + c] = s;
}

// ---- fused: v-reduce -> s -> squash -> [out] -> [t], W slice in LDS --------
__global__ __launch_bounds__(256) void k_sst(
    const float* __restrict__ src, int count, int bS, int nS, int cS,
    float scale, const float* __restrict__ W, float* __restrict__ tb,
    float* __restrict__ outp, int writeT) {
  int bn = blockIdx.x, b = bn >> 5, n = bn & 31;
  int tid = threadIdx.x;
  __shared__ unsigned short Wl[256][68];  // bf16 W[:, 64n:64n+64], row 136 B
  __shared__ float vs[Cn];
  __shared__ float red[Cn];
  __shared__ float ol[Dn];
  {  // stage W slice coalesced (float4 -> bf16); 4096 float4, 16/thread
    const float* wb = W + (size_t)n * Dn;
#pragma unroll
    for (int k = 0; k < 16; ++k) {
      int idx = tid + k * 256;        // 256 rows x 16 quads
      int row = idx >> 4, q = idx & 15;
      const float4 w4 = *(const float4*)&wb[(size_t)row * ND + q * 4];
      *(uint2*)&Wl[row][q * 4] = make_uint2(packbf2(w4.x, w4.y), packbf2(w4.z, w4.w));
    }
  }
  {  // v-reduce (lanes = c, coalesced 1 KB per chunk)
    const float* p = src + (size_t)b * bS + (size_t)n * nS + tid;
    float s = 0.f;
    for (int ch = 0; ch < count; ++ch) s += p[(size_t)ch * cS];
    vs[tid] = s * scale;
  }
  __syncthreads();
  {  // s partials: thread (q = tid>>6, d = tid&63) covers 64 c's; LDS reads free
    int q = tid >> 6, d = tid & 63;
    float a = 0.f;
#pragma unroll 8
    for (int c2 = 0; c2 < 64; ++c2) {
      float wv = __uint_as_float((unsigned int)Wl[q * 64 + c2][d] << 16);
      a += vs[q * 64 + c2] * wv;
    }
    red[tid] = a;
  }
  __syncthreads();
  if (tid < 64) {  // squash (one full wave)
    float a = red[tid] + red[64 + tid] + red[128 + tid] + red[192 + tid];
    float sq = a * a;
#pragma unroll
    for (int off = 32; off > 0; off >>= 1) sq += __shfl_xor(sq, off, 64);
    float o = a / sqrtf(sq + 1e-7f);
    ol[tid] = o;
    if (outp) outp[(size_t)bn * Dn + tid] = o;
  }
  __syncthreads();
  if (writeT) {  // t[c] = sum_d ol[d] * Wl[c][d]; ol broadcast, <=4-way LDS
    float a = 0.f;
#pragma unroll
    for (int d4 = 0; d4 < 16; ++d4) {
      const uint2 ww = *(const uint2*)&Wl[tid][d4 * 4];
      float f0 = __uint_as_float(ww.x << 16);
      float f1 = __uint_as_float(ww.x & 0xffff0000u);
      float f2 = __uint_as_float(ww.y << 16);
      float f3 = __uint_as_float(ww.y & 0xffff0000u);
      a += f0 * ol[d4 * 4] + f1 * ol[d4 * 4 + 1] +
           f2 * ol[d4 * 4 + 2] + f3 * ol[d4 * 4 + 3];
    }
    tb[(size_t)bn * Cn + tid] = a;
  }
}

// ---- fused routing step (MFMA): bb = u.t^T -> softmax -> pv = c.u ----------
// Block (b, it): i-tile of 32, 256 threads (4 waves).
__global__ __launch_bounds__(256, 3) void k_route(
    const float* __restrict__ tb, const float* __restrict__ u,
    float* __restrict__ pv) {
  const int b = blockIdx.x, itile = blockIdx.y, i0 = itile * 32;
  const int tid = threadIdx.x;
  const int lane = tid & 63, w = tid >> 6;
  const int mrow = lane & 15, quad = lane >> 4;

  __shared__ unsigned short t_l[32][272];   // bf16, row 544 B (16B-mult, 8-bank skew)
  __shared__ unsigned short u_t[256][40];   // bf16 i-major, row 80 B
  __shared__ unsigned short cm_l[32][40];   // bf16 softmax(c), row 80 B
  __shared__ float bb_l[32][36];

  // ---- stage: t (row-major bf16) + u_t (i-major bf16 scatter) ----
  {
    const float* tp = tb + (size_t)b * Nn * Cn;
    const float* up = u + ((size_t)(b * In + i0)) * Cn;
#pragma unroll
    for (int k = 0; k < 8; ++k) {
      int idx = tid + k * 256;           // 2048 = 32 rows x 64 quads
      int row = idx >> 6, q = idx & 63;
      const float4 tv = *(const float4*)&tp[(size_t)row * Cn + q * 4];
      *(uint2*)&t_l[row][q * 4] =
          make_uint2(packbf2(tv.x, tv.y), packbf2(tv.z, tv.w));
      const float4 uv = *(const float4*)&up[(size_t)row * Cn + q * 4];
      u_t[q * 4 + 0][row] = packbf1(uv.x);
      u_t[q * 4 + 1][row] = packbf1(uv.y);
      u_t[q * 4 + 2][row] = packbf1(uv.z);
      u_t[q * 4 + 3][row] = packbf1(uv.w);
    }
  }
  __syncthreads();

  // ---- phase A: D[i,n] = sum_c u[i,c] t[n,c]; wave tile (i0t, n0t) ----
  {
    const int i0t = (w & 1) * 16, n0t = (w >> 1) * 16;
    const float* ub = u + ((size_t)(b * In + i0 + i0t + mrow)) * Cn + quad * 8;
    f32x4 acc = {0.f, 0.f, 0.f, 0.f};
#pragma unroll
    for (int k0 = 0; k0 < 8; ++k0) {       // c = k0*32 + quad*8 + j
      const float4 a0 = *(const float4*)(ub + k0 * 32);
      const float4 a1 = *(const float4*)(ub + k0 * 32 + 4);
      union { unsigned int ui[4]; bf16x8 v; } af;
      af.ui[0] = packbf2(a0.x, a0.y); af.ui[1] = packbf2(a0.z, a0.w);
      af.ui[2] = packbf2(a1.x, a1.y); af.ui[3] = packbf2(a1.z, a1.w);
      const bf16x8 bf = *(const bf16x8*)&t_l[n0t + mrow][k0 * 32 + quad * 8];
      acc = __builtin_amdgcn_mfma_f32_16x16x32_bf16(af.v, bf, acc, 0, 0, 0);
    }
    // D: col=lane&15 -> n within tile, row=quad*4+reg -> i within tile
#pragma unroll
    for (int r = 0; r < 4; ++r)
      bb_l[n0t + mrow][i0t + quad * 4 + r] = acc[r];
  }
  __syncthreads();

  // ---- softmax over n per i ----
  if (tid < 32) {
    float m = -1e30f;
#pragma unroll
    for (int n = 0; n < Nn; ++n) m = fmaxf(m, bb_l[n][tid]);
    float e[Nn];
    float ssum = 0.f;
#pragma unroll
    for (int n = 0; n < Nn; ++n) { e[n] = __expf(bb_l[n][tid] - m); ssum += e[n]; }
    float inv = 1.f / ssum;
#pragma unroll
    for (int n = 0; n < Nn; ++n) bb_l[n][tid] = e[n] * inv;
  }
  __syncthreads();

  // ---- pack c to bf16 (cm_l), 256 threads x 4 elems ----
  {
    int n = tid >> 3, q = tid & 7;
    const float4 cv = *(const float4*)&bb_l[n][q * 4];
    *(uint2*)&cm_l[n][q * 4] = make_uint2(packbf2(cv.x, cv.y), packbf2(cv.z, cv.w));
  }
  __syncthreads();

  // ---- phase B: D[n,c] = sum_i c[n,i] u[i,c]; K=32 -> 1 MFMA/tile ----
  {
    const int mt = w & 1;                  // ncap tile (0..1)
    const bf16x8 af = *(const bf16x8*)&cm_l[mt * 16 + mrow][quad * 8];
#pragma unroll
    for (int j = 0; j < 8; ++j) {
      const int ct = (w >> 1) * 8 + j;     // c tile (0..15)
      const bf16x8 bf = *(const bf16x8*)&u_t[ct * 16 + mrow][quad * 8];
      f32x4 d = {0.f, 0.f, 0.f, 0.f};
      d = __builtin_amdgcn_mfma_f32_16x16x32_bf16(af, bf, d, 0, 0, 0);
      // D: col=lane&15 -> c within tile, row=quad*4+reg -> ncap within tile
#pragma unroll
      for (int r = 0; r < 4; ++r)
        pv[((size_t)((b * 32 + itile) * Nn + mt * 16 + quad * 4 + r)) * Cn +
           ct * 16 + mrow] = d[r];
    }
  }
}

extern "C" void kernel_launch(void* const* d_in, const int* in_sizes, int n_in,
                              void* d_out, int out_size, void* d_ws, size_t ws_size,
                              hipStream_t stream) {
  (void)in_sizes; (void)n_in; (void)out_size; (void)ws_size;
  const float* u = (const float*)d_in[0];   // (32,1024,256)
  const float* W = (const float*)d_in[1];   // (256,2048)
  float* out = (float*)d_out;               // (32,32,64)
  float* ws = (float*)d_ws;
  // workspace (floats): pv 32*32*32*256 = 8388608 (33.6 MB; psu 262144
  // overlaid -- consumed by sst0 before route writes pv), tb 262144.
  float* pv  = ws;
  float* psu = ws;
  float* tbb = ws + 8388608;

  k_colsum<<<dim3(32, 32), 256, 0, stream>>>(u, psu);
  // iter 0: v0 = colsum/32  (psu: b*8192 + ch*256 + c)
  k_sst<<<1024, 256, 0, stream>>>(psu, 32, 8192, 0, 256, 1.0f / 32.0f,
                                  W, tbb, nullptr, 1);
  // iter 1
  k_route<<<dim3(32, 32), 256, 0, stream>>>(tbb, u, pv);
  // pv: b*262144 + it*8192 + n*256 + c
  k_sst<<<1024, 256, 0, stream>>>(pv, 32, 262144, 256, 8192, 1.0f,
                                  W, tbb, nullptr, 1);
  // iter 2 (final)
  k_route<<<dim3(32, 32), 256, 0, stream>>>(tbb, u, pv);
  k_sst<<<1024, 256, 0, stream>>>(pv, 32, 262144, 256, 8192, 1.0f,
                                  W, tbb, out, 0);
}

// Round 8
// 160.763 us; speedup vs baseline: 2.0896x; 1.0093x over previous
//
#include <hip/hip_runtime.h>
#include <math.h>

// Capsule routing, u_hat never materialized (factors through W):
//   v[b,n,c] = sum_i c[b,n,i] u[b,i,c]
//   s[b,n,d] = sum_c v[b,n,c] W[c,n*64+d];  o = squash(s)
//   t[b,n,c] = sum_d o[b,n,d] W[c,n*64+d]
//   b[b,n,i] = sum_c t[b,n,c] u[b,i,c]
// Iter 0: b=0 -> c uniform 1/32 -> v0 = colsum(u)/32.
//
// R8: k_route's u_t scatter was ~32-way bank-conflicted (lanes shared the
// column index and spanned rows: lane stride 4 rows x 40 sh = 80 dw == 16
// mod 32 -> 2 banks per ds_write_b16). Any 16B-aligned row stride keeps that
// pattern >=32-way, so the WRITE PATTERN changes: lane-transposed staging
// (thread (i=tid&31, q=tid>>5) reads u[i][4q..4q+3] from global (L2-hot,
// 32 lines/wave) and writes consecutive shorts u_t[4q+j][i] -> 16 dw +
// 16-bank-offset halves = conflict-free). LDS drops to 37.4 KB -> 4 blk/CU.
// grid.sync stays banned (R4: ~1000us spin, 516MB WRITE).

constexpr int Bn = 32, In = 1024, Cn = 256, Nn = 32, Dn = 64, ND = 2048;

typedef __attribute__((ext_vector_type(8))) short bf16x8;
typedef __attribute__((ext_vector_type(4))) float f32x4;

__device__ __forceinline__ unsigned int packbf2(float a, float b) {
  unsigned int xa = __float_as_uint(a), xb = __float_as_uint(b);
  xa = (xa + 0x7fffu + ((xa >> 16) & 1u)) >> 16;  // RNE
  xb = (xb + 0x7fffu + ((xb >> 16) & 1u)) >> 16;
  return xa | (xb << 16);
}
__device__ __forceinline__ unsigned short packbf1(float a) {
  unsigned int x = __float_as_uint(a);
  return (unsigned short)((x + 0x7fffu + ((x >> 16) & 1u)) >> 16);
}

// ---------------- psu[(b*32+ch)*256+c] = sum over 32 i of u[b,i,c] ----------
__global__ __launch_bounds__(256) void k_colsum(const float* __restrict__ u,
                                                float* __restrict__ psu) {
  int b = blockIdx.x, ch = blockIdx.y, c = threadIdx.x;
  const float* up = u + ((size_t)(b * In + ch * 32)) * Cn + c;
  float s = 0.f;
#pragma unroll 8
  for (int j = 0; j < 32; ++j) s += up[(size_t)j * Cn];
  psu[(size_t)(b * 32 + ch) * Cn + c] = s;
}

// ---- fused: v-reduce -> s -> squash -> [out] -> [t], W slice in LDS --------
__global__ __launch_bounds__(256) void k_sst(
    const float* __restrict__ src, int count, int bS, int nS, int cS,
    float scale, const float* __restrict__ W, float* __restrict__ tb,
    float* __restrict__ outp, int writeT) {
  int bn = blockIdx.x, b = bn >> 5, n = bn & 31;
  int tid = threadIdx.x;
  __shared__ unsigned short Wl[256][68];  // bf16 W[:, 64n:64n+64], row 136 B
  __shared__ float vs[Cn];
  __shared__ float red[Cn];
  __shared__ float ol[Dn];
  {  // stage W slice coalesced (float4 -> bf16); 4096 float4, 16/thread
    const float* wb = W + (size_t)n * Dn;
#pragma unroll
    for (int k = 0; k < 16; ++k) {
      int idx = tid + k * 256;        // 256 rows x 16 quads
      int row = idx >> 4, q = idx & 15;
      const float4 w4 = *(const float4*)&wb[(size_t)row * ND + q * 4];
      *(uint2*)&Wl[row][q * 4] = make_uint2(packbf2(w4.x, w4.y), packbf2(w4.z, w4.w));
    }
  }
  {  // v-reduce (lanes = c, coalesced 1 KB per chunk)
    const float* p = src + (size_t)b * bS + (size_t)n * nS + tid;
    float s = 0.f;
    for (int ch = 0; ch < count; ++ch) s += p[(size_t)ch * cS];
    vs[tid] = s * scale;
  }
  __syncthreads();
  {  // s partials: thread (q = tid>>6, d = tid&63) covers 64 c's
    int q = tid >> 6, d = tid & 63;
    float a = 0.f;
#pragma unroll 8
    for (int c2 = 0; c2 < 64; ++c2) {
      float wv = __uint_as_float((unsigned int)Wl[q * 64 + c2][d] << 16);
      a += vs[q * 64 + c2] * wv;
    }
    red[tid] = a;
  }
  __syncthreads();
  if (tid < 64) {  // squash (one full wave)
    float a = red[tid] + red[64 + tid] + red[128 + tid] + red[192 + tid];
    float sq = a * a;
#pragma unroll
    for (int off = 32; off > 0; off >>= 1) sq += __shfl_xor(sq, off, 64);
    float o = a / sqrtf(sq + 1e-7f);
    ol[tid] = o;
    if (outp) outp[(size_t)bn * Dn + tid] = o;
  }
  __syncthreads();
  if (writeT) {  // t[c] = sum_d ol[d] * Wl[c][d]; ol broadcast, <=4-way LDS
    float a = 0.f;
#pragma unroll
    for (int d4 = 0; d4 < 16; ++d4) {
      const uint2 ww = *(const uint2*)&Wl[tid][d4 * 4];
      float f0 = __uint_as_float(ww.x << 16);
      float f1 = __uint_as_float(ww.x & 0xffff0000u);
      float f2 = __uint_as_float(ww.y << 16);
      float f3 = __uint_as_float(ww.y & 0xffff0000u);
      a += f0 * ol[d4 * 4] + f1 * ol[d4 * 4 + 1] +
           f2 * ol[d4 * 4 + 2] + f3 * ol[d4 * 4 + 3];
    }
    tb[(size_t)bn * Cn + tid] = a;
  }
}

// ---- fused routing step (MFMA): bb = u.t^T -> softmax -> pv = c.u ----------
// Block (b, it): i-tile of 32, 256 threads (4 waves). LDS 37.4 KB -> 4/CU.
__global__ __launch_bounds__(256, 4) void k_route(
    const float* __restrict__ tb, const float* __restrict__ u,
    float* __restrict__ pv) {
  const int b = blockIdx.x, itile = blockIdx.y, i0 = itile * 32;
  const int tid = threadIdx.x;
  const int lane = tid & 63, w = tid >> 6;
  const int mrow = lane & 15, quad = lane >> 4;

  __shared__ unsigned short t_l[32][264];   // bf16; row 528 B (16B-mult)
  __shared__ unsigned short u_t[256][40];   // bf16 i-major; row 80 B (16B-mult)
  __shared__ unsigned short cm_l[32][40];   // bf16 softmax(c)
  __shared__ float bb_l[32][36];

  // ---- stage t (coalesced) + u_t (lane-transposed reads, conflict-free) ----
  {
    const float* tp = tb + (size_t)b * Nn * Cn;
#pragma unroll
    for (int k = 0; k < 8; ++k) {
      int idx = tid + k * 256;           // 2048 = 32 rows x 64 quads
      int row = idx >> 6, q = idx & 63;
      const float4 tv = *(const float4*)&tp[(size_t)row * Cn + q * 4];
      *(uint2*)&t_l[row][q * 4] =
          make_uint2(packbf2(tv.x, tv.y), packbf2(tv.z, tv.w));
    }
    // u_t: thread (i = tid&31, qb = tid>>5); lanes span i -> LDS writes are
    // consecutive shorts (16 dw) with +16-bank offset halves: conflict-free.
    const int ti = tid & 31, qb = tid >> 5;
    const float* up = u + ((size_t)(b * In + i0 + ti)) * Cn;
#pragma unroll
    for (int m = 0; m < 8; ++m) {
      int q = qb + m * 8;
      const float4 uv = *(const float4*)&up[q * 4];
      u_t[q * 4 + 0][ti] = packbf1(uv.x);
      u_t[q * 4 + 1][ti] = packbf1(uv.y);
      u_t[q * 4 + 2][ti] = packbf1(uv.z);
      u_t[q * 4 + 3][ti] = packbf1(uv.w);
    }
  }
  __syncthreads();

  // ---- phase A: D[i,n] = sum_c u[i,c] t[n,c]; wave tile (i0t, n0t) ----
  {
    const int i0t = (w & 1) * 16, n0t = (w >> 1) * 16;
    const float* ub = u + ((size_t)(b * In + i0 + i0t + mrow)) * Cn + quad * 8;
    f32x4 acc = {0.f, 0.f, 0.f, 0.f};
#pragma unroll
    for (int k0 = 0; k0 < 8; ++k0) {       // c = k0*32 + quad*8 + j
      const float4 a0 = *(const float4*)(ub + k0 * 32);
      const float4 a1 = *(const float4*)(ub + k0 * 32 + 4);
      union { unsigned int ui[4]; bf16x8 v; } af;
      af.ui[0] = packbf2(a0.x, a0.y); af.ui[1] = packbf2(a0.z, a0.w);
      af.ui[2] = packbf2(a1.x, a1.y); af.ui[3] = packbf2(a1.z, a1.w);
      const bf16x8 bf = *(const bf16x8*)&t_l[n0t + mrow][k0 * 32 + quad * 8];
      acc = __builtin_amdgcn_mfma_f32_16x16x32_bf16(af.v, bf, acc, 0, 0, 0);
    }
    // D: col=lane&15 -> n within tile, row=quad*4+reg -> i within tile
#pragma unroll
    for (int r = 0; r < 4; ++r)
      bb_l[n0t + mrow][i0t + quad * 4 + r] = acc[r];
  }
  __syncthreads();

  // ---- softmax over n per i ----
  if (tid < 32) {
    float m = -1e30f;
#pragma unroll
    for (int n = 0; n < Nn; ++n) m = fmaxf(m, bb_l[n][tid]);
    float e[Nn];
    float ssum = 0.f;
#pragma unroll
    for (int n = 0; n < Nn; ++n) { e[n] = __expf(bb_l[n][tid] - m); ssum += e[n]; }
    float inv = 1.f / ssum;
#pragma unroll
    for (int n = 0; n < Nn; ++n) bb_l[n][tid] = e[n] * inv;
  }
  __syncthreads();

  // ---- pack c to bf16 (cm_l), 256 threads x 4 elems ----
  {
    int n = tid >> 3, q = tid & 7;
    const float4 cv = *(const float4*)&bb_l[n][q * 4];
    *(uint2*)&cm_l[n][q * 4] = make_uint2(packbf2(cv.x, cv.y), packbf2(cv.z, cv.w));
  }
  __syncthreads();

  // ---- phase B: D[n,c] = sum_i c[n,i] u[i,c]; K=32 -> 1 MFMA/tile ----
  {
    const int mt = w & 1;                  // ncap tile (0..1)
    const bf16x8 af = *(const bf16x8*)&cm_l[mt * 16 + mrow][quad * 8];
#pragma unroll
    for (int j = 0; j < 8; ++j) {
      const int ct = (w >> 1) * 8 + j;     // c tile (0..15)
      const bf16x8 bf = *(const bf16x8*)&u_t[ct * 16 + mrow][quad * 8];
      f32x4 d = {0.f, 0.f, 0.f, 0.f};
      d = __builtin_amdgcn_mfma_f32_16x16x32_bf16(af, bf, d, 0, 0, 0);
      // D: col=lane&15 -> c within tile, row=quad*4+reg -> ncap within tile
#pragma unroll
      for (int r = 0; r < 4; ++r)
        pv[((size_t)((b * 32 + itile) * Nn + mt * 16 + quad * 4 + r)) * Cn +
           ct * 16 + mrow] = d[r];
    }
  }
}

extern "C" void kernel_launch(void* const* d_in, const int* in_sizes, int n_in,
                              void* d_out, int out_size, void* d_ws, size_t ws_size,
                              hipStream_t stream) {
  (void)in_sizes; (void)n_in; (void)out_size; (void)ws_size;
  const float* u = (const float*)d_in[0];   // (32,1024,256)
  const float* W = (const float*)d_in[1];   // (256,2048)
  float* out = (float*)d_out;               // (32,32,64)
  float* ws = (float*)d_ws;
  // workspace (floats): pv 32*32*32*256 = 8388608 (33.6 MB; psu 262144
  // overlaid -- consumed by sst0 before route writes pv), tb 262144.
  float* pv  = ws;
  float* psu = ws;
  float* tbb = ws + 8388608;

  k_colsum<<<dim3(32, 32), 256, 0, stream>>>(u, psu);
  // iter 0: v0 = colsum/32  (psu: b*8192 + ch*256 + c)
  k_sst<<<1024, 256, 0, stream>>>(psu, 32, 8192, 0, 256, 1.0f / 32.0f,
                                  W, tbb, nullptr, 1);
  // iter 1
  k_route<<<dim3(32, 32), 256, 0, stream>>>(tbb, u, pv);
  // pv: b*262144 + it*8192 + n*256 + c
  k_sst<<<1024, 256, 0, stream>>>(pv, 32, 262144, 256, 8192, 1.0f,
                                  W, tbb, nullptr, 1);
  // iter 2 (final)
  k_route<<<dim3(32, 32), 256, 0, stream>>>(tbb, u, pv);
  k_sst<<<1024, 256, 0, stream>>>(pv, 32, 262144, 256, 8192, 1.0f,
                                  W, tbb, out, 0);
}

// Round 9
// 158.892 us; speedup vs baseline: 2.1141x; 1.0118x over previous
//
#include <hip/hip_runtime.h>
#include <math.h>

// Capsule routing, u_hat never materialized (factors through W):
//   v[b,n,c] = sum_i c[b,n,i] u[b,i,c]
//   s[b,n,d] = sum_c v[b,n,c] W[c,n*64+d];  o = squash(s)
//   t[b,n,c] = sum_d o[b,n,d] W[c,n*64+d]
//   b[b,n,i] = sum_c t[b,n,c] u[b,i,c]
// Iter 0: b=0 -> c uniform 1/32 -> v0 = colsum(u)/32.
//
// R9: diet round. k_pre (replaces k_colsum, same chain depth) additionally
// builds W as bf16 in BOTH layouts (Wbf[c][nd], WbfT[nd][c], 8 MB each,
// L3-hot since written this launch). k_sst loses its whole 64 KB/block LDS
// W-staging phase (was re-done 32x per n; 64 MB aggregate + pack VALU) and
// reads W coalesced from L2/L3 in the compute loops. pv partials stored as
// bf16 (halves the 67 MB/iter pv round trip; same summation order).
// grid.sync stays banned (R4: ~1000us spin). Route MFMA structure from R8.

constexpr int Bn = 32, In = 1024, Cn = 256, Nn = 32, Dn = 64, ND = 2048;

typedef __attribute__((ext_vector_type(8))) short bf16x8;
typedef __attribute__((ext_vector_type(4))) float f32x4;

__device__ __forceinline__ unsigned int packbf2(float a, float b) {
  unsigned int xa = __float_as_uint(a), xb = __float_as_uint(b);
  xa = (xa + 0x7fffu + ((xa >> 16) & 1u)) >> 16;  // RNE
  xb = (xb + 0x7fffu + ((xb >> 16) & 1u)) >> 16;
  return xa | (xb << 16);
}
__device__ __forceinline__ unsigned short packbf1(float a) {
  unsigned int x = __float_as_uint(a);
  return (unsigned short)((x + 0x7fffu + ((x >> 16) & 1u)) >> 16);
}
__device__ __forceinline__ float bfu(unsigned short us) {
  return __uint_as_float((unsigned int)us << 16);
}

// ---- k_pre: colsum (z<1024) | WbfT transpose (1024..1151) | Wbf cast -------
__global__ __launch_bounds__(256) void k_pre(
    const float* __restrict__ u, const float* __restrict__ W,
    float* __restrict__ psu, unsigned short* __restrict__ Wbf,
    unsigned short* __restrict__ WbfT) {
  const int z = blockIdx.x, tid = threadIdx.x;
  if (z < 1024) {  // colsum: psu[z*256+c] = sum over 32 i of u[b, ch*32+i, c]
    int b = z >> 5, ch = z & 31;
    const float* up = u + ((size_t)(b * In + ch * 32)) * Cn + tid;
    float s = 0.f;
#pragma unroll 8
    for (int j = 0; j < 32; ++j) s += up[(size_t)j * Cn];
    psu[(size_t)z * Cn + tid] = s;
  } else if (z < 1152) {  // WbfT[nd][c] = bf16(W[c][nd]), 64x64 tiles
    __shared__ float tile[64][65];
    int t = z - 1024;
    int x0 = (t & 31) * 64, y0 = (t >> 5) * 64;  // x=nd, y=c
    int lx = tid & 63, ly = tid >> 6;
#pragma unroll
    for (int k = 0; k < 16; ++k) {
      int y = ly + k * 4;
      tile[y][lx] = W[(size_t)(y0 + y) * ND + x0 + lx];
    }
    __syncthreads();
#pragma unroll
    for (int k = 0; k < 8; ++k) {  // 64 rows x 32 uints
      int idx = tid + k * 256;
      int row = idx >> 5, cu = idx & 31;
      unsigned int v = packbf2(tile[2 * cu][row], tile[2 * cu + 1][row]);
      *(unsigned int*)&WbfT[(size_t)(x0 + row) * Cn + y0 + 2 * cu] = v;
    }
  } else {  // Wbf: straight cast, 128 blocks x 4096 floats
    int zb = z - 1152;
    const float* src = W + (size_t)zb * 4096;
    unsigned short* dst = Wbf + (size_t)zb * 4096;
#pragma unroll
    for (int k = 0; k < 4; ++k) {
      int off = k * 1024 + tid * 4;
      const float4 v = *(const float4*)&src[off];
      *(uint2*)&dst[off] = make_uint2(packbf2(v.x, v.y), packbf2(v.z, v.w));
    }
  }
}

// ---- fused: v-reduce -> s -> squash -> [out] -> [t]; W read from L2/L3 -----
__global__ __launch_bounds__(256) void k_sst(
    const void* __restrict__ src, int srcBf16, int count, long bS, long nS,
    long cS, float scale, const unsigned short* __restrict__ Wbf,
    const unsigned short* __restrict__ WbfT, float* __restrict__ tb,
    float* __restrict__ outp, int writeT) {
  int bn = blockIdx.x, b = bn >> 5, n = bn & 31;
  int tid = threadIdx.x;
  __shared__ float vs[Cn];
  __shared__ float red[Cn];
  __shared__ float ol[Dn];
  {  // v-reduce (lanes = c, coalesced)
    float s = 0.f;
    if (srcBf16) {
      const unsigned short* p = (const unsigned short*)src + b * bS + n * nS + tid;
      for (int ch = 0; ch < count; ++ch) s += bfu(p[(size_t)ch * cS]);
    } else {
      const float* p = (const float*)src + b * bS + n * nS + tid;
      for (int ch = 0; ch < count; ++ch) s += p[(size_t)ch * cS];
    }
    vs[tid] = s * scale;
  }
  __syncthreads();
  {  // s partials: thread (q = tid>>6, d = tid&63); Wbf rows 128 B coalesced
    int q = tid >> 6, d = tid & 63;
    const unsigned short* wp = Wbf + (size_t)(q * 64) * ND + (size_t)n * Dn + d;
    float a = 0.f;
#pragma unroll 8
    for (int c2 = 0; c2 < 64; ++c2) a += vs[q * 64 + c2] * bfu(wp[(size_t)c2 * ND]);
    red[tid] = a;
  }
  __syncthreads();
  if (tid < 64) {  // squash (one full wave)
    float a = red[tid] + red[64 + tid] + red[128 + tid] + red[192 + tid];
    float sq = a * a;
#pragma unroll
    for (int off = 32; off > 0; off >>= 1) sq += __shfl_xor(sq, off, 64);
    float o = a / sqrtf(sq + 1e-7f);
    ol[tid] = o;
    if (outp) outp[(size_t)bn * Dn + tid] = o;
  }
  __syncthreads();
  if (writeT) {  // t[c] = sum_d ol[d] * WbfT[n*64+d][c]; 512 B coalesced rows
    const unsigned short* wt = WbfT + (size_t)(n * Dn) * Cn + tid;
    float a = 0.f;
#pragma unroll 8
    for (int d2 = 0; d2 < 64; ++d2) a += ol[d2] * bfu(wt[(size_t)d2 * Cn]);
    tb[(size_t)bn * Cn + tid] = a;
  }
}

// ---- fused routing step (MFMA): bb = u.t^T -> softmax -> pv = c.u ----------
// Block (b, it): i-tile of 32, 256 threads (4 waves). pv stored bf16.
__global__ __launch_bounds__(256, 4) void k_route(
    const float* __restrict__ tb, const float* __restrict__ u,
    unsigned short* __restrict__ pvb) {
  const int b = blockIdx.x, itile = blockIdx.y, i0 = itile * 32;
  const int tid = threadIdx.x;
  const int lane = tid & 63, w = tid >> 6;
  const int mrow = lane & 15, quad = lane >> 4;

  __shared__ unsigned short t_l[32][264];   // bf16; row 528 B (16B-mult)
  __shared__ unsigned short u_t[256][40];   // bf16 i-major; row 80 B
  __shared__ unsigned short cm_l[32][40];   // bf16 softmax(c)
  __shared__ float bb_l[32][36];

  // ---- stage t (coalesced) + u_t (lane-transposed reads, conflict-free) ----
  {
    const float* tp = tb + (size_t)b * Nn * Cn;
#pragma unroll
    for (int k = 0; k < 8; ++k) {
      int idx = tid + k * 256;           // 2048 = 32 rows x 64 quads
      int row = idx >> 6, q = idx & 63;
      const float4 tv = *(const float4*)&tp[(size_t)row * Cn + q * 4];
      *(uint2*)&t_l[row][q * 4] =
          make_uint2(packbf2(tv.x, tv.y), packbf2(tv.z, tv.w));
    }
    const int ti = tid & 31, qb = tid >> 5;
    const float* up = u + ((size_t)(b * In + i0 + ti)) * Cn;
#pragma unroll
    for (int m = 0; m < 8; ++m) {
      int q = qb + m * 8;
      const float4 uv = *(const float4*)&up[q * 4];
      u_t[q * 4 + 0][ti] = packbf1(uv.x);
      u_t[q * 4 + 1][ti] = packbf1(uv.y);
      u_t[q * 4 + 2][ti] = packbf1(uv.z);
      u_t[q * 4 + 3][ti] = packbf1(uv.w);
    }
  }
  __syncthreads();

  // ---- phase A: D[i,n] = sum_c u[i,c] t[n,c]; wave tile (i0t, n0t) ----
  {
    const int i0t = (w & 1) * 16, n0t = (w >> 1) * 16;
    const float* ub = u + ((size_t)(b * In + i0 + i0t + mrow)) * Cn + quad * 8;
    f32x4 acc = {0.f, 0.f, 0.f, 0.f};
#pragma unroll
    for (int k0 = 0; k0 < 8; ++k0) {       // c = k0*32 + quad*8 + j
      const float4 a0 = *(const float4*)(ub + k0 * 32);
      const float4 a1 = *(const float4*)(ub + k0 * 32 + 4);
      union { unsigned int ui[4]; bf16x8 v; } af;
      af.ui[0] = packbf2(a0.x, a0.y); af.ui[1] = packbf2(a0.z, a0.w);
      af.ui[2] = packbf2(a1.x, a1.y); af.ui[3] = packbf2(a1.z, a1.w);
      const bf16x8 bf = *(const bf16x8*)&t_l[n0t + mrow][k0 * 32 + quad * 8];
      acc = __builtin_amdgcn_mfma_f32_16x16x32_bf16(af.v, bf, acc, 0, 0, 0);
    }
    // D: col=lane&15 -> n within tile, row=quad*4+reg -> i within tile
#pragma unroll
    for (int r = 0; r < 4; ++r)
      bb_l[n0t + mrow][i0t + quad * 4 + r] = acc[r];
  }
  __syncthreads();

  // ---- softmax over n per i ----
  if (tid < 32) {
    float m = -1e30f;
#pragma unroll
    for (int n = 0; n < Nn; ++n) m = fmaxf(m, bb_l[n][tid]);
    float e[Nn];
    float ssum = 0.f;
#pragma unroll
    for (int n = 0; n < Nn; ++n) { e[n] = __expf(bb_l[n][tid] - m); ssum += e[n]; }
    float inv = 1.f / ssum;
#pragma unroll
    for (int n = 0; n < Nn; ++n) bb_l[n][tid] = e[n] * inv;
  }
  __syncthreads();

  // ---- pack c to bf16 (cm_l), 256 threads x 4 elems ----
  {
    int n = tid >> 3, q = tid & 7;
    const float4 cv = *(const float4*)&bb_l[n][q * 4];
    *(uint2*)&cm_l[n][q * 4] = make_uint2(packbf2(cv.x, cv.y), packbf2(cv.z, cv.w));
  }
  __syncthreads();

  // ---- phase B: D[n,c] = sum_i c[n,i] u[i,c]; K=32 -> 1 MFMA/tile ----
  {
    const int mt = w & 1;                  // ncap tile (0..1)
    const bf16x8 af = *(const bf16x8*)&cm_l[mt * 16 + mrow][quad * 8];
#pragma unroll
    for (int j = 0; j < 8; ++j) {
      const int ct = (w >> 1) * 8 + j;     // c tile (0..15)
      const bf16x8 bf = *(const bf16x8*)&u_t[ct * 16 + mrow][quad * 8];
      f32x4 d = {0.f, 0.f, 0.f, 0.f};
      d = __builtin_amdgcn_mfma_f32_16x16x32_bf16(af, bf, d, 0, 0, 0);
      // D: col=lane&15 -> c within tile, row=quad*4+reg -> ncap within tile
#pragma unroll
      for (int r = 0; r < 4; ++r)
        pvb[((size_t)((b * 32 + itile) * Nn + mt * 16 + quad * 4 + r)) * Cn +
            ct * 16 + mrow] = packbf1(d[r]);
    }
  }
}

extern "C" void kernel_launch(void* const* d_in, const int* in_sizes, int n_in,
                              void* d_out, int out_size, void* d_ws, size_t ws_size,
                              hipStream_t stream) {
  (void)in_sizes; (void)n_in; (void)out_size; (void)ws_size;
  const float* u = (const float*)d_in[0];   // (32,1024,256)
  const float* W = (const float*)d_in[1];   // (256,2048)
  float* out = (float*)d_out;               // (32,32,64)
  float* ws = (float*)d_ws;
  // ws layout (float units): pvb bf16 8388608 ush = 4194304 | psu 262144 |
  // Wbf 524288 ush = 262144 | WbfT 262144 | tb 262144  => 21 MB total.
  unsigned short* pvb  = (unsigned short*)ws;
  float*          psu  = ws + 4194304;
  unsigned short* Wbf  = (unsigned short*)(ws + 4456448);
  unsigned short* WbfT = (unsigned short*)(ws + 4718592);
  float*          tbb  = ws + 4980736;

  k_pre<<<1280, 256, 0, stream>>>(u, W, psu, Wbf, WbfT);
  // iter 0: v0 = colsum/32 (psu fp32: b-stride 8192, ch-stride 256)
  k_sst<<<1024, 256, 0, stream>>>(psu, 0, 32, 8192L, 0L, 256L, 1.0f / 32.0f,
                                  Wbf, WbfT, tbb, nullptr, 1);
  // iter 1
  k_route<<<dim3(32, 32), 256, 0, stream>>>(tbb, u, pvb);
  // pvb bf16: b-stride 262144, n-stride 256, it-stride 8192 (ushort units)
  k_sst<<<1024, 256, 0, stream>>>(pvb, 1, 32, 262144L, 256L, 8192L, 1.0f,
                                  Wbf, WbfT, tbb, nullptr, 1);
  // iter 2 (final)
  k_route<<<dim3(32, 32), 256, 0, stream>>>(tbb, u, pvb);
  k_sst<<<1024, 256, 0, stream>>>(pvb, 1, 32, 262144L, 256L, 8192L, 1.0f,
                                  Wbf, WbfT, tbb, out, 0);
}